// Round 4
// baseline (57.865 us; speedup 1.0000x reference)
//
#include <hip/hip_runtime.h>
#include <hip/hip_bf16.h>

// PWL monotone interpolation, N=2097152, C=16, B=32.
// out = a[c,seg]*x + b[c,seg].
// seg via 5-level binary search: levels 1-3 in registers (28 preloaded VGPRs),
// levels 4-5 + a,b gathers from BANK-PRIVATE replicated LDS tables:
// lane uses table copy at bank (lane&31) -> every gather conflict-free.

#define C_CH 16
#define B_KN 32
#define TAB_WORDS 12288   // 32 banks * 4 ch * 3 arrays * 32 words = 48 KB

// ws float layout: [0..511]=xs(c*32+k), [512..1023]=a(c*32+s), [1024..1535]=b

// ---------------- setup: sort knots, cumsum ys, per-segment a,b ----------------
__global__ __launch_bounds__(512) void pwl_setup_kernel(
    const float* __restrict__ xp, const float* __restrict__ y0,
    const float* __restrict__ dy, float* __restrict__ ws) {
    __shared__ float s_x[C_CH][B_KN];
    __shared__ float s_xs[C_CH][B_KN];
    __shared__ float s_ys[C_CH][B_KN];
    int t = threadIdx.x;
    int c = t >> 5;
    int k = t & 31;
    float v = xp[c * B_KN + k];
    s_x[c][k] = v;
    __syncthreads();
    int rank = 0;
#pragma unroll
    for (int j = 0; j < B_KN; ++j) {
        float u = s_x[c][j];
        rank += (u < v || (u == v && j < k)) ? 1 : 0;
    }
    s_xs[c][rank] = v;
    float acc = y0[c];
    for (int j = 0; j < k; ++j) acc += fabsf(dy[c * (B_KN - 1) + j]);
    s_ys[c][k] = acc;
    __syncthreads();
    ws[c * B_KN + k] = s_xs[c][k];
    if (k < B_KN - 1) {
        float x0 = s_xs[c][k], x1 = s_xs[c][k + 1];
        float ya = s_ys[c][k], yb = s_ys[c][k + 1];
        float a = (yb - ya) / (x1 - x0);
        float b = ya - a * x0;
        ws[512 + c * B_KN + k]  = a;
        ws[1024 + c * B_KN + k] = b;
    } else {
        ws[512 + c * B_KN + k]  = 0.0f;   // seg never reaches 31
        ws[1024 + c * B_KN + k] = 0.0f;
    }
}

// ---------------- main ----------------
// LDS word index: ((j*96 + arr*32 + idx) << 5) | bank,  arr: 0=xs 1=a 2=b,
// j = local channel (0..3), channel c = (bank&3)*4 + j.
__global__ __launch_bounds__(512, 6) void pwl_main_kernel(
    const float4* __restrict__ x, float4* __restrict__ out,
    const float* __restrict__ ws, int n4) {
    __shared__ float s_tab[TAB_WORDS];
    int t = threadIdx.x;
    // fill bank-private tables (24 iters)
    for (int w = t; w < TAB_WORDS; w += 512) {
        int bk = w & 31;
        int r  = w >> 5;
        int m  = r / 96;
        int tt = r - m * 96;
        int arr = tt >> 5;
        int idx = tt & 31;
        int c = ((bk & 3) << 2) + m;
        s_tab[w] = ws[arr * 512 + c * 32 + idx];
    }
    // preload register search levels 1-3 for this lane's 4 channels
    int c0 = (t & 3) << 2;
    float v15[4], v7[4], v23[4], v3[4], v11[4], v19[4], v27[4];
#pragma unroll
    for (int j = 0; j < 4; ++j) {
        const float* xs = ws + (c0 + j) * B_KN;
        v15[j] = xs[15];
        v7[j]  = xs[7];
        v23[j] = xs[23];
        v3[j]  = xs[3];
        v11[j] = xs[11];
        v19[j] = xs[19];
        v27[j] = xs[27];
    }
    __syncthreads();

    int bk = t & 31;
    int tid = blockIdx.x * 512 + t;
    int stride = gridDim.x * 512;

    int i = tid;
    if (i >= n4) return;
    float4 v = x[i];
    while (true) {
        int inext = i + stride;
        float4 vn = v;
        if (inext < n4) vn = x[inext];   // keep next load in flight
        float xv[4] = {v.x, v.y, v.z, v.w};
        float r[4];
#pragma unroll
        for (int j = 0; j < 4; ++j) {
            float xq = xv[j];
            // levels 1-3: registers
            bool b16 = (v15[j] < xq);
            float l2v = b16 ? v23[j] : v7[j];
            bool b8 = (l2v < xq);
            float l3a = b16 ? v19[j] : v3[j];
            float l3b = b16 ? v27[j] : v11[j];
            float l3v = b8 ? l3b : l3a;
            bool b4 = (l3v < xq);
            int pos = (b16 ? 16 : 0) + (b8 ? 8 : 0) + (b4 ? 4 : 0);
            // levels 4-5: bank-private LDS (conflict-free)
            float w1 = s_tab[((j * 96 + (pos + 1)) << 5) | bk];
            pos += (w1 < xq) ? 2 : 0;
            float w2 = s_tab[((j * 96 + pos) << 5) | bk];
            pos += (w2 < xq) ? 1 : 0;
            int seg = pos < 2 ? 0 : (pos > 31 ? 30 : pos - 1);  // clip(pos,1,31)-1
            float a = s_tab[((j * 96 + 32 + seg) << 5) | bk];
            float b = s_tab[((j * 96 + 64 + seg) << 5) | bk];
            r[j] = fmaf(a, xq, b);
        }
        out[i] = make_float4(r[0], r[1], r[2], r[3]);
        if (inext >= n4) break;
        i = inext;
        v = vn;
    }
}

extern "C" void kernel_launch(void* const* d_in, const int* in_sizes, int n_in,
                              void* d_out, int out_size, void* d_ws, size_t ws_size,
                              hipStream_t stream) {
    const float* x  = (const float*)d_in[0];
    const float* xp = (const float*)d_in[1];
    const float* y0 = (const float*)d_in[2];
    const float* dy = (const float*)d_in[3];
    float* out = (float*)d_out;
    float* ws  = (float*)d_ws;

    pwl_setup_kernel<<<1, 512, 0, stream>>>(xp, y0, dy, ws);

    int n4 = in_sizes[0] / 4;  // 8388608
    int blocks = 768;          // 3 blocks/CU (LDS-limited), grid-stride
    pwl_main_kernel<<<blocks, 512, 0, stream>>>((const float4*)x, (float4*)out, ws, n4);
}